// Round 5
// baseline (17441.119 us; speedup 1.0000x reference)
//
#include <hip/hip_runtime.h>
#include <hip/hip_cooperative_groups.h>

// LSTM: B=64, T=256, IN=512, H=1024 (4H=4096), OUT=512. I/O is FLOAT32
// (reference dtype; round-4 proved bf16-input reads NaN => inputs are f32).
// Single fused cooperative kernel, 256 blocks x 256 thr, ws = 512 KiB
// (h ping-pong stored as bf16 hi+lo pairs for precision).
//   block p: gate slab j in [4p,4p+4) -> 16 gate cols {i,f,g,o}x4; W slab
//            (1536x16) rounded to bf16, resident in LDS (~48KB).
//            out-proj tile: batches [8*(p>>5),+8) x cols [16*(p&31),+16),
//            Wo fragments (step-invariant) hoisted into 32 VGPRs.
//   per step t: gate MFMA for t (x split hi/lo on the fly; h read as hi/lo
//            frags -> A-side exact, only W single-rounded) + out-proj MFMA
//            for t-1 -> syncthreads -> ew update (f32) writes h_t hi/lo;
//            reduce obuf -> out[:, t-1, :] -> ONE grid.sync per step.

#define B_   64
#define T_   256
#define IN_  512
#define H_   1024
#define G4_  4096
#define OUT_ 512
#define KTOT 1536   // IN_ + H_

typedef __bf16 bf8v  __attribute__((ext_vector_type(8)));
typedef float  f4v   __attribute__((ext_vector_type(4)));

__device__ __forceinline__ float sigm(float x) { return 1.f / (1.f + __expf(-x)); }
__device__ __forceinline__ float tanh_f(float x) { return 1.f - 2.f / (__expf(2.f * x) + 1.f); }

__global__ void __launch_bounds__(256)
lstm_fused(const float* __restrict__ xs, const float* __restrict__ Wi,
           const float* __restrict__ Wh, const float* __restrict__ bias,
           const float* __restrict__ Wo, const float* __restrict__ bo,
           float* __restrict__ out, __bf16* __restrict__ hws)
{
    __shared__ __bf16 Wlds[16][KTOT + 8];   // ~48.3 KB (bf16-rounded weights)
    __shared__ float  gbuf[64][17];         // 4.3 KB
    __shared__ float  obuf[4][16][17];      // 4.3 KB   (total ~57 KB)

    const int tid = threadIdx.x;
    const int blk = blockIdx.x;       // 0..255
    const int j0  = blk * 4;
    const int ob0 = (blk >> 5) * 8;   // out-proj batch group (8 batches)
    const int oc0 = (blk & 31) * 16;  // out-proj col group (16 cols)

    // Stage resident gate-weight slab (f32 -> bf16)
    for (int idx = tid; idx < 16 * KTOT; idx += 256) {
        int k = idx >> 4, c = idx & 15;
        int gc = (c >> 2) * H_ + j0 + (c & 3);
        float w = (k < IN_) ? Wi[(size_t)k * G4_ + gc]
                            : Wh[(size_t)(k - IN_) * G4_ + gc];
        Wlds[c][k] = (__bf16)w;
    }
    __syncthreads();

    const int lane = tid & 63;
    const int wave = tid >> 6;
    const int c    = lane & 15;
    const int quad = lane >> 4;
    const int rowA = wave * 16 + c;   // batch row for gate A-frags
    const int kq   = quad * 8;

    const float biasv = bias[(c >> 2) * H_ + j0 + (c & 3)];

    // Hoist step-invariant Wo fragments into registers (f32 -> bf16)
    bf8v wof[8];
    #pragma unroll
    for (int kk = 0; kk < 8; ++kk) {
        int kbase = wave * 256 + kk * 32 + kq;
        #pragma unroll
        for (int j = 0; j < 8; ++j)
            wof[kk][j] = (__bf16)Wo[(size_t)(kbase + j) * OUT_ + oc0 + c];
    }

    // recurrent cell state: thread owns (batch = tid>>2, j = j0 + (tid&3))
    float c_reg = 0.f;
    const int bb = tid >> 2;
    const int jo = tid & 3;

    // h ws layout: [buf(2)][part hi/lo][B][H] bf16
    for (int t = 0; t < T_; ++t) {
        const __bf16* hhi_p = hws + (size_t)(t & 1) * (2 * B_ * H_);
        const __bf16* hlo_p = hhi_p + B_ * H_;
        __bf16* hhi_c = hws + (size_t)((t + 1) & 1) * (2 * B_ * H_);
        __bf16* hlo_c = hhi_c + B_ * H_;

        // ---- phase A: gate MFMA for step t ----
        f4v acc0 = {0.f, 0.f, 0.f, 0.f};   // hi-product chain
        f4v acc1 = {0.f, 0.f, 0.f, 0.f};   // lo-product chain
        const float* xrow = xs + ((size_t)rowA * T_ + t) * IN_ + kq;
        #pragma unroll
        for (int ks = 0; ks < 16; ++ks) {
            f4v v0 = *(const f4v*)(xrow + ks * 32);
            f4v v1 = *(const f4v*)(xrow + ks * 32 + 4);
            bf8v ah, al;
            #pragma unroll
            for (int j = 0; j < 4; ++j) {
                __bf16 h0 = (__bf16)v0[j], h1 = (__bf16)v1[j];
                ah[j] = h0;  ah[4 + j] = h1;
                al[j]     = (__bf16)(v0[j] - (float)h0);
                al[4 + j] = (__bf16)(v1[j] - (float)h1);
            }
            bf8v w = *(const bf8v*)&Wlds[c][ks * 32 + kq];
            acc0 = __builtin_amdgcn_mfma_f32_16x16x32_bf16(ah, w, acc0, 0, 0, 0);
            acc1 = __builtin_amdgcn_mfma_f32_16x16x32_bf16(al, w, acc1, 0, 0, 0);
        }
        if (t > 0) {
            const __bf16* hh = hhi_p + (size_t)rowA * H_ + kq;
            const __bf16* hl = hlo_p + (size_t)rowA * H_ + kq;
            #pragma unroll
            for (int ks = 0; ks < 32; ++ks) {
                bf8v ah = *(const bf8v*)(hh + ks * 32);
                bf8v al = *(const bf8v*)(hl + ks * 32);
                bf8v w  = *(const bf8v*)&Wlds[c][IN_ + ks * 32 + kq];
                acc0 = __builtin_amdgcn_mfma_f32_16x16x32_bf16(ah, w, acc0, 0, 0, 0);
                acc1 = __builtin_amdgcn_mfma_f32_16x16x32_bf16(al, w, acc1, 0, 0, 0);
            }
        }
        f4v acc = acc0 + acc1;
        #pragma unroll
        for (int r = 0; r < 4; ++r)
            gbuf[wave * 16 + quad * 4 + r][c] = acc[r] + biasv;  // C: col=c, row=quad*4+r

        // ---- phase A2: out-proj partial for step t-1 (reads same h_{t-1}) ----
        if (t > 0) {
            f4v oac = {0.f, 0.f, 0.f, 0.f};
            #pragma unroll
            for (int kk = 0; kk < 8; ++kk) {
                int kbase = wave * 256 + kk * 32 + kq;
                bf8v ah = {}, al = {};
                if (c < 8) {   // A rows 8..15 zero (8 batches per tile)
                    ah = *(const bf8v*)&hhi_p[(size_t)(ob0 + c) * H_ + kbase];
                    al = *(const bf8v*)&hlo_p[(size_t)(ob0 + c) * H_ + kbase];
                }
                oac = __builtin_amdgcn_mfma_f32_16x16x32_bf16(ah, wof[kk], oac, 0, 0, 0);
                oac = __builtin_amdgcn_mfma_f32_16x16x32_bf16(al, wof[kk], oac, 0, 0, 0);
            }
            #pragma unroll
            for (int r = 0; r < 4; ++r)
                obuf[wave][quad * 4 + r][c] = oac[r];
        }
        __syncthreads();

        // ---- phase B: elementwise cell update, write h_t (hi+lo) ----
        {
            float gi = gbuf[bb][jo];
            float gf = gbuf[bb][4 + jo];
            float gg = gbuf[bb][8 + jo];
            float go = gbuf[bb][12 + jo];
            c_reg = sigm(gf) * c_reg + sigm(gi) * tanh_f(gg);
            float hn = sigm(go) * tanh_f(c_reg);
            __bf16 hh = (__bf16)hn;
            hhi_c[(size_t)bb * H_ + j0 + jo] = hh;
            hlo_c[(size_t)bb * H_ + j0 + jo] = (__bf16)(hn - (float)hh);
        }
        // ---- phase B2: reduce out-proj partials, store out[:, t-1, :] ----
        if (t > 0 && tid < 128) {
            int m = tid >> 4, cc = tid & 15;
            float v = obuf[0][m][cc] + obuf[1][m][cc] + obuf[2][m][cc] + obuf[3][m][cc]
                    + bo[oc0 + cc];
            out[(((size_t)(ob0 + m)) * T_ + (t - 1)) * OUT_ + oc0 + cc] = v;
        }

        __threadfence();
        cooperative_groups::this_grid().sync();   // publish h_t; guards gbuf/obuf WAR
    }

    // ---- epilogue: out-proj for t = T-1 (h_{T-1} is in buffer 0; T even) ----
    {
        const __bf16* hhi_l = hws;
        const __bf16* hlo_l = hws + B_ * H_;
        f4v oac = {0.f, 0.f, 0.f, 0.f};
        #pragma unroll
        for (int kk = 0; kk < 8; ++kk) {
            int kbase = wave * 256 + kk * 32 + kq;
            bf8v ah = {}, al = {};
            if (c < 8) {
                ah = *(const bf8v*)&hhi_l[(size_t)(ob0 + c) * H_ + kbase];
                al = *(const bf8v*)&hlo_l[(size_t)(ob0 + c) * H_ + kbase];
            }
            oac = __builtin_amdgcn_mfma_f32_16x16x32_bf16(ah, wof[kk], oac, 0, 0, 0);
            oac = __builtin_amdgcn_mfma_f32_16x16x32_bf16(al, wof[kk], oac, 0, 0, 0);
        }
        #pragma unroll
        for (int r = 0; r < 4; ++r)
            obuf[wave][quad * 4 + r][c] = oac[r];
        __syncthreads();
        if (tid < 128) {
            int m = tid >> 4, cc = tid & 15;
            float v = obuf[0][m][cc] + obuf[1][m][cc] + obuf[2][m][cc] + obuf[3][m][cc]
                    + bo[oc0 + cc];
            out[(((size_t)(ob0 + m)) * T_ + (T_ - 1)) * OUT_ + oc0 + cc] = v;
        }
    }
}

extern "C" void kernel_launch(void* const* d_in, const int* in_sizes, int n_in,
                              void* d_out, int out_size, void* d_ws, size_t ws_size,
                              hipStream_t stream) {
    const float* xs = (const float*)d_in[0];
    const float* Wi = (const float*)d_in[1];
    const float* Wh = (const float*)d_in[2];
    const float* b  = (const float*)d_in[3];
    const float* Wo = (const float*)d_in[4];
    const float* bo = (const float*)d_in[5];
    float* out = (float*)d_out;
    __bf16* hws = (__bf16*)d_ws;   // 2 bufs x (hi+lo) x B x H bf16 = 512 KiB

    void* args[] = {(void*)&xs, (void*)&Wi, (void*)&Wh, (void*)&b,
                    (void*)&Wo, (void*)&bo, (void*)&out, (void*)&hws};
    hipLaunchCooperativeKernel((void*)lstm_fused, dim3(256), dim3(256), args, 0, stream);
}

// Round 6
// 9932.252 us; speedup vs baseline: 1.7560x; 1.7560x over previous
//
#include <hip/hip_runtime.h>
#include <hip/hip_cooperative_groups.h>

// LSTM: B=64, T=256, IN=512, H=1024 (4H=4096), OUT=512. I/O f32.
// Round-6: replace (threadfence + CG grid.sync)  [~65 us/step, 93% of runtime]
// with a hand-rolled monotonic device-scope barrier (~2-4 us/step):
//   - 8 sub-counters (blk&7) absorb arrival contention; last arriver of each
//     sub-group increments root; thread0 spins ACQUIRE on root, s_sleep backoff.
//   - RELEASE fetch_add makes this block's h stores (already drained to L2 by
//     __syncthreads) visible agent-wide; ACQUIRE spin-load invalidates stale
//     L1/L2 lines before readers proceed. Monotonic counts: no reset races.
//   - counters in d_ws[0..256), zeroed each launch by captured hipMemsetAsync;
//     h ping-pong (bf16 hi+lo, 512 KiB) at d_ws + 64 KiB.
// Compute path identical to round 5 (absmax 7.8e-3).

#define B_   64
#define T_   256
#define IN_  512
#define H_   1024
#define G4_  4096
#define OUT_ 512
#define KTOT 1536   // IN_ + H_

typedef __bf16 bf8v  __attribute__((ext_vector_type(8)));
typedef float  f4v   __attribute__((ext_vector_type(4)));

__device__ __forceinline__ float sigm(float x) { return 1.f / (1.f + __expf(-x)); }
__device__ __forceinline__ float tanh_f(float x) { return 1.f - 2.f / (__expf(2.f * x) + 1.f); }

// Monotonic all-block barrier: t-th use expects cnt8[g] -> 32*(t+1), root -> 8*(t+1).
__device__ __forceinline__ void grid_barrier(unsigned* cnt8, unsigned* root,
                                             int t, int blk) {
    __syncthreads();   // drains vmcnt: this block's h stores are in L2
    if (threadIdx.x == 0) {
        unsigned a = __hip_atomic_fetch_add(&cnt8[blk & 7], 1u,
                                            __ATOMIC_ACQ_REL, __HIP_MEMORY_SCOPE_AGENT);
        if (a == 32u * (unsigned)(t + 1) - 1u)   // last arriver of this sub-group
            __hip_atomic_fetch_add(root, 1u,
                                   __ATOMIC_ACQ_REL, __HIP_MEMORY_SCOPE_AGENT);
        while (__hip_atomic_load(root, __ATOMIC_ACQUIRE, __HIP_MEMORY_SCOPE_AGENT)
               < 8u * (unsigned)(t + 1))
            __builtin_amdgcn_s_sleep(2);
    }
    __syncthreads();
}

__global__ void __launch_bounds__(256)
lstm_fused(const float* __restrict__ xs, const float* __restrict__ Wi,
           const float* __restrict__ Wh, const float* __restrict__ bias,
           const float* __restrict__ Wo, const float* __restrict__ bo,
           float* __restrict__ out, __bf16* __restrict__ hws,
           unsigned* __restrict__ cnt8, unsigned* __restrict__ root)
{
    __shared__ __bf16 Wlds[16][KTOT + 8];   // ~48.3 KB (bf16-rounded weights)
    __shared__ float  gbuf[64][17];         // 4.3 KB
    __shared__ float  obuf[4][16][17];      // 4.3 KB   (total ~57 KB)

    const int tid = threadIdx.x;
    const int blk = blockIdx.x;       // 0..255
    const int j0  = blk * 4;
    const int ob0 = (blk >> 5) * 8;   // out-proj batch group (8 batches)
    const int oc0 = (blk & 31) * 16;  // out-proj col group (16 cols)

    // Stage resident gate-weight slab (f32 -> bf16)
    for (int idx = tid; idx < 16 * KTOT; idx += 256) {
        int k = idx >> 4, c = idx & 15;
        int gc = (c >> 2) * H_ + j0 + (c & 3);
        float w = (k < IN_) ? Wi[(size_t)k * G4_ + gc]
                            : Wh[(size_t)(k - IN_) * G4_ + gc];
        Wlds[c][k] = (__bf16)w;
    }
    __syncthreads();

    const int lane = tid & 63;
    const int wave = tid >> 6;
    const int c    = lane & 15;
    const int quad = lane >> 4;
    const int rowA = wave * 16 + c;   // batch row for gate A-frags
    const int kq   = quad * 8;

    const float biasv = bias[(c >> 2) * H_ + j0 + (c & 3)];

    // Hoist step-invariant Wo fragments into registers (f32 -> bf16)
    bf8v wof[8];
    #pragma unroll
    for (int kk = 0; kk < 8; ++kk) {
        int kbase = wave * 256 + kk * 32 + kq;
        #pragma unroll
        for (int j = 0; j < 8; ++j)
            wof[kk][j] = (__bf16)Wo[(size_t)(kbase + j) * OUT_ + oc0 + c];
    }

    // recurrent cell state: thread owns (batch = tid>>2, j = j0 + (tid&3))
    float c_reg = 0.f;
    const int bb = tid >> 2;
    const int jo = tid & 3;

    // h ws layout: [buf(2)][part hi/lo][B][H] bf16
    for (int t = 0; t < T_; ++t) {
        const __bf16* hhi_p = hws + (size_t)(t & 1) * (2 * B_ * H_);
        const __bf16* hlo_p = hhi_p + B_ * H_;
        __bf16* hhi_c = hws + (size_t)((t + 1) & 1) * (2 * B_ * H_);
        __bf16* hlo_c = hhi_c + B_ * H_;

        // ---- phase A: gate MFMA for step t ----
        f4v acc0 = {0.f, 0.f, 0.f, 0.f};   // hi-product chain
        f4v acc1 = {0.f, 0.f, 0.f, 0.f};   // lo-product chain
        const float* xrow = xs + ((size_t)rowA * T_ + t) * IN_ + kq;
        #pragma unroll
        for (int ks = 0; ks < 16; ++ks) {
            f4v v0 = *(const f4v*)(xrow + ks * 32);
            f4v v1 = *(const f4v*)(xrow + ks * 32 + 4);
            bf8v ah, al;
            #pragma unroll
            for (int j = 0; j < 4; ++j) {
                __bf16 h0 = (__bf16)v0[j], h1 = (__bf16)v1[j];
                ah[j] = h0;  ah[4 + j] = h1;
                al[j]     = (__bf16)(v0[j] - (float)h0);
                al[4 + j] = (__bf16)(v1[j] - (float)h1);
            }
            bf8v w = *(const bf8v*)&Wlds[c][ks * 32 + kq];
            acc0 = __builtin_amdgcn_mfma_f32_16x16x32_bf16(ah, w, acc0, 0, 0, 0);
            acc1 = __builtin_amdgcn_mfma_f32_16x16x32_bf16(al, w, acc1, 0, 0, 0);
        }
        if (t > 0) {
            const __bf16* hh = hhi_p + (size_t)rowA * H_ + kq;
            const __bf16* hl = hlo_p + (size_t)rowA * H_ + kq;
            #pragma unroll
            for (int ks = 0; ks < 32; ++ks) {
                bf8v ah = *(const bf8v*)(hh + ks * 32);
                bf8v al = *(const bf8v*)(hl + ks * 32);
                bf8v w  = *(const bf8v*)&Wlds[c][IN_ + ks * 32 + kq];
                acc0 = __builtin_amdgcn_mfma_f32_16x16x32_bf16(ah, w, acc0, 0, 0, 0);
                acc1 = __builtin_amdgcn_mfma_f32_16x16x32_bf16(al, w, acc1, 0, 0, 0);
            }
        }
        f4v acc = acc0 + acc1;
        #pragma unroll
        for (int r = 0; r < 4; ++r)
            gbuf[wave * 16 + quad * 4 + r][c] = acc[r] + biasv;  // C: col=c, row=quad*4+r

        // ---- phase A2: out-proj partial for step t-1 (reads same h_{t-1}) ----
        if (t > 0) {
            f4v oac = {0.f, 0.f, 0.f, 0.f};
            #pragma unroll
            for (int kk = 0; kk < 8; ++kk) {
                int kbase = wave * 256 + kk * 32 + kq;
                bf8v ah = {}, al = {};
                if (c < 8) {   // A rows 8..15 zero (8 batches per tile)
                    ah = *(const bf8v*)&hhi_p[(size_t)(ob0 + c) * H_ + kbase];
                    al = *(const bf8v*)&hlo_p[(size_t)(ob0 + c) * H_ + kbase];
                }
                oac = __builtin_amdgcn_mfma_f32_16x16x32_bf16(ah, wof[kk], oac, 0, 0, 0);
                oac = __builtin_amdgcn_mfma_f32_16x16x32_bf16(al, wof[kk], oac, 0, 0, 0);
            }
            #pragma unroll
            for (int r = 0; r < 4; ++r)
                obuf[wave][quad * 4 + r][c] = oac[r];
        }
        __syncthreads();

        // ---- phase B: elementwise cell update, write h_t (hi+lo) ----
        {
            float gi = gbuf[bb][jo];
            float gf = gbuf[bb][4 + jo];
            float gg = gbuf[bb][8 + jo];
            float go = gbuf[bb][12 + jo];
            c_reg = sigm(gf) * c_reg + sigm(gi) * tanh_f(gg);
            float hn = sigm(go) * tanh_f(c_reg);
            __bf16 hh = (__bf16)hn;
            hhi_c[(size_t)bb * H_ + j0 + jo] = hh;
            hlo_c[(size_t)bb * H_ + j0 + jo] = (__bf16)(hn - (float)hh);
        }
        // ---- phase B2: reduce out-proj partials, store out[:, t-1, :] ----
        if (t > 0 && tid < 128) {
            int m = tid >> 4, cc = tid & 15;
            float v = obuf[0][m][cc] + obuf[1][m][cc] + obuf[2][m][cc] + obuf[3][m][cc]
                    + bo[oc0 + cc];
            out[(((size_t)(ob0 + m)) * T_ + (t - 1)) * OUT_ + oc0 + cc] = v;
        }

        grid_barrier(cnt8, root, t, blk);   // publish h_t; guards gbuf/obuf WAR
    }

    // ---- epilogue: out-proj for t = T-1 (h_{T-1} is in buffer 0; T even) ----
    {
        const __bf16* hhi_l = hws;
        const __bf16* hlo_l = hws + B_ * H_;
        f4v oac = {0.f, 0.f, 0.f, 0.f};
        #pragma unroll
        for (int kk = 0; kk < 8; ++kk) {
            int kbase = wave * 256 + kk * 32 + kq;
            bf8v ah = {}, al = {};
            if (c < 8) {
                ah = *(const bf8v*)&hhi_l[(size_t)(ob0 + c) * H_ + kbase];
                al = *(const bf8v*)&hlo_l[(size_t)(ob0 + c) * H_ + kbase];
            }
            oac = __builtin_amdgcn_mfma_f32_16x16x32_bf16(ah, wof[kk], oac, 0, 0, 0);
            oac = __builtin_amdgcn_mfma_f32_16x16x32_bf16(al, wof[kk], oac, 0, 0, 0);
        }
        #pragma unroll
        for (int r = 0; r < 4; ++r)
            obuf[wave][quad * 4 + r][c] = oac[r];
        __syncthreads();
        if (tid < 128) {
            int m = tid >> 4, cc = tid & 15;
            float v = obuf[0][m][cc] + obuf[1][m][cc] + obuf[2][m][cc] + obuf[3][m][cc]
                    + bo[oc0 + cc];
            out[(((size_t)(ob0 + m)) * T_ + (T_ - 1)) * OUT_ + oc0 + cc] = v;
        }
    }
}

extern "C" void kernel_launch(void* const* d_in, const int* in_sizes, int n_in,
                              void* d_out, int out_size, void* d_ws, size_t ws_size,
                              hipStream_t stream) {
    const float* xs = (const float*)d_in[0];
    const float* Wi = (const float*)d_in[1];
    const float* Wh = (const float*)d_in[2];
    const float* b  = (const float*)d_in[3];
    const float* Wo = (const float*)d_in[4];
    const float* bo = (const float*)d_in[5];
    float* out = (float*)d_out;

    // ws layout: [0,256): barrier counters (zeroed每 launch); [64K, 64K+512K): h
    unsigned* cnt8 = (unsigned*)d_ws;          // 8 sub-counters
    unsigned* root = cnt8 + 8;                 // root counter
    __bf16*   hws  = (__bf16*)((char*)d_ws + 65536);

    hipMemsetAsync(d_ws, 0, 256, stream);      // reset barrier counters (captured)

    void* args[] = {(void*)&xs, (void*)&Wi, (void*)&Wh, (void*)&b,
                    (void*)&Wo, (void*)&bo, (void*)&out, (void*)&hws,
                    (void*)&cnt8, (void*)&root};
    hipLaunchCooperativeKernel((void*)lstm_fused, dim3(256), dim3(256), args, 0, stream);
}

// Round 9
// 8217.731 us; speedup vs baseline: 2.1224x; 1.2086x over previous
//
#include <hip/hip_runtime.h>
#include <hip/hip_cooperative_groups.h>

// LSTM: B=64, T=256, IN=512, H=1024 (4H=4096), OUT=512. I/O f32.
// Round-9 = round-6 source VERBATIM with exactly ONE change: barrier
// counters line-padded (each sub-counter and the root on its own 128B
// line). r6's 264 agent-RMWs/step all hit one L3 line -> serialized
// (~30us/step, matching the observed 38.8us/step residual).
// r7/r8 post-mortem: both produced the round-0 stub signature (absmax
// 454.0/1.0703) with normal test duration => the cooperative launch
// itself failed (error unchecked); cause was somewhere in the 5-change
// bundle. Lesson applied: bisect from the known-good r6 build, one
// variable per round.
// Compute path identical to r5/r6 (absmax 7.8e-3).

#define B_   64
#define T_   256
#define IN_  512
#define H_   1024
#define G4_  4096
#define OUT_ 512
#define KTOT 1536   // IN_ + H_

typedef __bf16 bf8v  __attribute__((ext_vector_type(8)));
typedef float  f4v   __attribute__((ext_vector_type(4)));

__device__ __forceinline__ float sigm(float x) { return 1.f / (1.f + __expf(-x)); }
__device__ __forceinline__ float tanh_f(float x) { return 1.f - 2.f / (__expf(2.f * x) + 1.f); }

// Monotonic all-block barrier. cnt8[g] lives at cnt8[g*32] (one 128B line per
// counter); root is its own line. t-th use: cnt -> 32*(t+1), root -> 8*(t+1).
__device__ __forceinline__ void grid_barrier(unsigned* cnt8, unsigned* root,
                                             int t, int blk) {
    __syncthreads();   // drains vmcnt: this block's h stores are in L2
    if (threadIdx.x == 0) {
        unsigned a = __hip_atomic_fetch_add(&cnt8[(blk & 7) * 32], 1u,
                                            __ATOMIC_ACQ_REL, __HIP_MEMORY_SCOPE_AGENT);
        if (a == 32u * (unsigned)(t + 1) - 1u)   // last arriver of this sub-group
            __hip_atomic_fetch_add(root, 1u,
                                   __ATOMIC_ACQ_REL, __HIP_MEMORY_SCOPE_AGENT);
        while (__hip_atomic_load(root, __ATOMIC_ACQUIRE, __HIP_MEMORY_SCOPE_AGENT)
               < 8u * (unsigned)(t + 1))
            __builtin_amdgcn_s_sleep(2);
    }
    __syncthreads();
}

__global__ void __launch_bounds__(256)
lstm_fused(const float* __restrict__ xs, const float* __restrict__ Wi,
           const float* __restrict__ Wh, const float* __restrict__ bias,
           const float* __restrict__ Wo, const float* __restrict__ bo,
           float* __restrict__ out, __bf16* __restrict__ hws,
           unsigned* __restrict__ cnt8, unsigned* __restrict__ root)
{
    __shared__ __bf16 Wlds[16][KTOT + 8];   // ~48.3 KB (bf16-rounded weights)
    __shared__ float  gbuf[64][17];         // 4.3 KB
    __shared__ float  obuf[4][16][17];      // 4.3 KB   (total ~57 KB)

    const int tid = threadIdx.x;
    const int blk = blockIdx.x;       // 0..255
    const int j0  = blk * 4;
    const int ob0 = (blk >> 5) * 8;   // out-proj batch group (8 batches)
    const int oc0 = (blk & 31) * 16;  // out-proj col group (16 cols)

    // Stage resident gate-weight slab (f32 -> bf16)
    for (int idx = tid; idx < 16 * KTOT; idx += 256) {
        int k = idx >> 4, c = idx & 15;
        int gc = (c >> 2) * H_ + j0 + (c & 3);
        float w = (k < IN_) ? Wi[(size_t)k * G4_ + gc]
                            : Wh[(size_t)(k - IN_) * G4_ + gc];
        Wlds[c][k] = (__bf16)w;
    }
    __syncthreads();

    const int lane = tid & 63;
    const int wave = tid >> 6;
    const int c    = lane & 15;
    const int quad = lane >> 4;
    const int rowA = wave * 16 + c;   // batch row for gate A-frags
    const int kq   = quad * 8;

    const float biasv = bias[(c >> 2) * H_ + j0 + (c & 3)];

    // Hoist step-invariant Wo fragments into registers (f32 -> bf16)
    bf8v wof[8];
    #pragma unroll
    for (int kk = 0; kk < 8; ++kk) {
        int kbase = wave * 256 + kk * 32 + kq;
        #pragma unroll
        for (int j = 0; j < 8; ++j)
            wof[kk][j] = (__bf16)Wo[(size_t)(kbase + j) * OUT_ + oc0 + c];
    }

    // recurrent cell state: thread owns (batch = tid>>2, j = j0 + (tid&3))
    float c_reg = 0.f;
    const int bb = tid >> 2;
    const int jo = tid & 3;

    // h ws layout: [buf(2)][part hi/lo][B][H] bf16
    for (int t = 0; t < T_; ++t) {
        const __bf16* hhi_p = hws + (size_t)(t & 1) * (2 * B_ * H_);
        const __bf16* hlo_p = hhi_p + B_ * H_;
        __bf16* hhi_c = hws + (size_t)((t + 1) & 1) * (2 * B_ * H_);
        __bf16* hlo_c = hhi_c + B_ * H_;

        // ---- phase A: gate MFMA for step t ----
        f4v acc0 = {0.f, 0.f, 0.f, 0.f};   // hi-product chain
        f4v acc1 = {0.f, 0.f, 0.f, 0.f};   // lo-product chain
        const float* xrow = xs + ((size_t)rowA * T_ + t) * IN_ + kq;
        #pragma unroll
        for (int ks = 0; ks < 16; ++ks) {
            f4v v0 = *(const f4v*)(xrow + ks * 32);
            f4v v1 = *(const f4v*)(xrow + ks * 32 + 4);
            bf8v ah, al;
            #pragma unroll
            for (int j = 0; j < 4; ++j) {
                __bf16 h0 = (__bf16)v0[j], h1 = (__bf16)v1[j];
                ah[j] = h0;  ah[4 + j] = h1;
                al[j]     = (__bf16)(v0[j] - (float)h0);
                al[4 + j] = (__bf16)(v1[j] - (float)h1);
            }
            bf8v w = *(const bf8v*)&Wlds[c][ks * 32 + kq];
            acc0 = __builtin_amdgcn_mfma_f32_16x16x32_bf16(ah, w, acc0, 0, 0, 0);
            acc1 = __builtin_amdgcn_mfma_f32_16x16x32_bf16(al, w, acc1, 0, 0, 0);
        }
        if (t > 0) {
            const __bf16* hh = hhi_p + (size_t)rowA * H_ + kq;
            const __bf16* hl = hlo_p + (size_t)rowA * H_ + kq;
            #pragma unroll
            for (int ks = 0; ks < 32; ++ks) {
                bf8v ah = *(const bf8v*)(hh + ks * 32);
                bf8v al = *(const bf8v*)(hl + ks * 32);
                bf8v w  = *(const bf8v*)&Wlds[c][IN_ + ks * 32 + kq];
                acc0 = __builtin_amdgcn_mfma_f32_16x16x32_bf16(ah, w, acc0, 0, 0, 0);
                acc1 = __builtin_amdgcn_mfma_f32_16x16x32_bf16(al, w, acc1, 0, 0, 0);
            }
        }
        f4v acc = acc0 + acc1;
        #pragma unroll
        for (int r = 0; r < 4; ++r)
            gbuf[wave * 16 + quad * 4 + r][c] = acc[r] + biasv;  // C: col=c, row=quad*4+r

        // ---- phase A2: out-proj partial for step t-1 (reads same h_{t-1}) ----
        if (t > 0) {
            f4v oac = {0.f, 0.f, 0.f, 0.f};
            #pragma unroll
            for (int kk = 0; kk < 8; ++kk) {
                int kbase = wave * 256 + kk * 32 + kq;
                bf8v ah = {}, al = {};
                if (c < 8) {   // A rows 8..15 zero (8 batches per tile)
                    ah = *(const bf8v*)&hhi_p[(size_t)(ob0 + c) * H_ + kbase];
                    al = *(const bf8v*)&hlo_p[(size_t)(ob0 + c) * H_ + kbase];
                }
                oac = __builtin_amdgcn_mfma_f32_16x16x32_bf16(ah, wof[kk], oac, 0, 0, 0);
                oac = __builtin_amdgcn_mfma_f32_16x16x32_bf16(al, wof[kk], oac, 0, 0, 0);
            }
            #pragma unroll
            for (int r = 0; r < 4; ++r)
                obuf[wave][quad * 4 + r][c] = oac[r];
        }
        __syncthreads();

        // ---- phase B: elementwise cell update, write h_t (hi+lo) ----
        {
            float gi = gbuf[bb][jo];
            float gf = gbuf[bb][4 + jo];
            float gg = gbuf[bb][8 + jo];
            float go = gbuf[bb][12 + jo];
            c_reg = sigm(gf) * c_reg + sigm(gi) * tanh_f(gg);
            float hn = sigm(go) * tanh_f(c_reg);
            __bf16 hh = (__bf16)hn;
            hhi_c[(size_t)bb * H_ + j0 + jo] = hh;
            hlo_c[(size_t)bb * H_ + j0 + jo] = (__bf16)(hn - (float)hh);
        }
        // ---- phase B2: reduce out-proj partials, store out[:, t-1, :] ----
        if (t > 0 && tid < 128) {
            int m = tid >> 4, cc = tid & 15;
            float v = obuf[0][m][cc] + obuf[1][m][cc] + obuf[2][m][cc] + obuf[3][m][cc]
                    + bo[oc0 + cc];
            out[(((size_t)(ob0 + m)) * T_ + (t - 1)) * OUT_ + oc0 + cc] = v;
        }

        grid_barrier(cnt8, root, t, blk);   // publish h_t; guards gbuf/obuf WAR
    }

    // ---- epilogue: out-proj for t = T-1 (h_{T-1} is in buffer 0; T even) ----
    {
        const __bf16* hhi_l = hws;
        const __bf16* hlo_l = hws + B_ * H_;
        f4v oac = {0.f, 0.f, 0.f, 0.f};
        #pragma unroll
        for (int kk = 0; kk < 8; ++kk) {
            int kbase = wave * 256 + kk * 32 + kq;
            bf8v ah = {}, al = {};
            if (c < 8) {
                ah = *(const bf8v*)&hhi_l[(size_t)(ob0 + c) * H_ + kbase];
                al = *(const bf8v*)&hlo_l[(size_t)(ob0 + c) * H_ + kbase];
            }
            oac = __builtin_amdgcn_mfma_f32_16x16x32_bf16(ah, wof[kk], oac, 0, 0, 0);
            oac = __builtin_amdgcn_mfma_f32_16x16x32_bf16(al, wof[kk], oac, 0, 0, 0);
        }
        #pragma unroll
        for (int r = 0; r < 4; ++r)
            obuf[wave][quad * 4 + r][c] = oac[r];
        __syncthreads();
        if (tid < 128) {
            int m = tid >> 4, cc = tid & 15;
            float v = obuf[0][m][cc] + obuf[1][m][cc] + obuf[2][m][cc] + obuf[3][m][cc]
                    + bo[oc0 + cc];
            out[(((size_t)(ob0 + m)) * T_ + (T_ - 1)) * OUT_ + oc0 + cc] = v;
        }
    }
}

extern "C" void kernel_launch(void* const* d_in, const int* in_sizes, int n_in,
                              void* d_out, int out_size, void* d_ws, size_t ws_size,
                              hipStream_t stream) {
    const float* xs = (const float*)d_in[0];
    const float* Wi = (const float*)d_in[1];
    const float* Wh = (const float*)d_in[2];
    const float* b  = (const float*)d_in[3];
    const float* Wo = (const float*)d_in[4];
    const float* bo = (const float*)d_in[5];
    float* out = (float*)d_out;

    // ws layout: [0,4K) barrier counters (line-padded, zeroed); [64K,+512K) h
    unsigned* cnt8 = (unsigned*)d_ws;          // 8 counters at cnt8[g*32]
    unsigned* root = cnt8 + 256;               // byte 1024: own 128B line
    __bf16*   hws  = (__bf16*)((char*)d_ws + 65536);

    hipMemsetAsync(d_ws, 0, 4096, stream);     // reset barrier counters (captured)

    void* args[] = {(void*)&xs, (void*)&Wi, (void*)&Wh, (void*)&b,
                    (void*)&Wo, (void*)&bo, (void*)&out, (void*)&hws,
                    (void*)&cnt8, (void*)&root};
    hipLaunchCooperativeKernel((void*)lstm_fused, dim3(256), dim3(256), args, 0, stream);
}

// Round 10
// 5851.878 us; speedup vs baseline: 2.9804x; 1.4043x over previous
//
#include <hip/hip_runtime.h>
#include <hip/hip_cooperative_groups.h>

// LSTM: B=64, T=256, IN=512, H=1024 (4H=4096), OUT=512. I/O f32.
// Round-10 = round-9 source with exactly ONE change: the barrier POLL.
//   r9 evidence: FETCH_SIZE 495 MB vs ~60 MB cold => ~8x refetch. Cause:
//   ACQUIRE-per-poll in bar_wait invalidates the local XCD caches every
//   ~200ns x 256 blocks -> caches disabled during the wait.
//   Fix: spin on RELAXED agent loads (sc1 cache-bypass load: fresh value,
//   no invalidate), ACQUIRE probe every 64 spins as progress hedge, ONE
//   acquire-agent fence after exit for h visibility.
//   (r7/r8's stub-absmax + normal runtime = launch failure, not livelock;
//   the relaxed-poll idea was never actually falsified.)
// Compute path identical to r5/r6/r9 (absmax 7.8e-3).

#define B_   64
#define T_   256
#define IN_  512
#define H_   1024
#define G4_  4096
#define OUT_ 512
#define KTOT 1536   // IN_ + H_

typedef __bf16 bf8v  __attribute__((ext_vector_type(8)));
typedef float  f4v   __attribute__((ext_vector_type(4)));

__device__ __forceinline__ float sigm(float x) { return 1.f / (1.f + __expf(-x)); }
__device__ __forceinline__ float tanh_f(float x) { return 1.f - 2.f / (__expf(2.f * x) + 1.f); }

// Monotonic all-block barrier. cnt8[g] at cnt8[g*32] (one 128B line each);
// root on its own line. t-th use: cnt -> 32*(t+1), root -> 8*(t+1).
__device__ __forceinline__ void grid_barrier(unsigned* cnt8, unsigned* root,
                                             int t, int blk) {
    __syncthreads();   // drains vmcnt: this block's h stores are in L2
    if (threadIdx.x == 0) {
        unsigned a = __hip_atomic_fetch_add(&cnt8[(blk & 7) * 32], 1u,
                                            __ATOMIC_ACQ_REL, __HIP_MEMORY_SCOPE_AGENT);
        if (a == 32u * (unsigned)(t + 1) - 1u)   // last arriver of this sub-group
            __hip_atomic_fetch_add(root, 1u,
                                   __ATOMIC_ACQ_REL, __HIP_MEMORY_SCOPE_AGENT);
        const unsigned tgt = 8u * (unsigned)(t + 1);
        int spins = 0;
        while (__hip_atomic_load(root, __ATOMIC_RELAXED,
                                 __HIP_MEMORY_SCOPE_AGENT) < tgt) {   // no invalidate
            __builtin_amdgcn_s_sleep(2);
            if ((++spins & 63) == 0 &&
                __hip_atomic_load(root, __ATOMIC_ACQUIRE,
                                  __HIP_MEMORY_SCOPE_AGENT) >= tgt)   // progress hedge
                break;
        }
        __builtin_amdgcn_fence(__ATOMIC_ACQUIRE, "agent");   // one invalidate: h visible
    }
    __syncthreads();
}

__global__ void __launch_bounds__(256)
lstm_fused(const float* __restrict__ xs, const float* __restrict__ Wi,
           const float* __restrict__ Wh, const float* __restrict__ bias,
           const float* __restrict__ Wo, const float* __restrict__ bo,
           float* __restrict__ out, __bf16* __restrict__ hws,
           unsigned* __restrict__ cnt8, unsigned* __restrict__ root)
{
    __shared__ __bf16 Wlds[16][KTOT + 8];   // ~48.3 KB (bf16-rounded weights)
    __shared__ float  gbuf[64][17];         // 4.3 KB
    __shared__ float  obuf[4][16][17];      // 4.3 KB   (total ~57 KB)

    const int tid = threadIdx.x;
    const int blk = blockIdx.x;       // 0..255
    const int j0  = blk * 4;
    const int ob0 = (blk >> 5) * 8;   // out-proj batch group (8 batches)
    const int oc0 = (blk & 31) * 16;  // out-proj col group (16 cols)

    // Stage resident gate-weight slab (f32 -> bf16)
    for (int idx = tid; idx < 16 * KTOT; idx += 256) {
        int k = idx >> 4, c = idx & 15;
        int gc = (c >> 2) * H_ + j0 + (c & 3);
        float w = (k < IN_) ? Wi[(size_t)k * G4_ + gc]
                            : Wh[(size_t)(k - IN_) * G4_ + gc];
        Wlds[c][k] = (__bf16)w;
    }
    __syncthreads();

    const int lane = tid & 63;
    const int wave = tid >> 6;
    const int c    = lane & 15;
    const int quad = lane >> 4;
    const int rowA = wave * 16 + c;   // batch row for gate A-frags
    const int kq   = quad * 8;

    const float biasv = bias[(c >> 2) * H_ + j0 + (c & 3)];

    // Hoist step-invariant Wo fragments into registers (f32 -> bf16)
    bf8v wof[8];
    #pragma unroll
    for (int kk = 0; kk < 8; ++kk) {
        int kbase = wave * 256 + kk * 32 + kq;
        #pragma unroll
        for (int j = 0; j < 8; ++j)
            wof[kk][j] = (__bf16)Wo[(size_t)(kbase + j) * OUT_ + oc0 + c];
    }

    // recurrent cell state: thread owns (batch = tid>>2, j = j0 + (tid&3))
    float c_reg = 0.f;
    const int bb = tid >> 2;
    const int jo = tid & 3;

    // h ws layout: [buf(2)][part hi/lo][B][H] bf16
    for (int t = 0; t < T_; ++t) {
        const __bf16* hhi_p = hws + (size_t)(t & 1) * (2 * B_ * H_);
        const __bf16* hlo_p = hhi_p + B_ * H_;
        __bf16* hhi_c = hws + (size_t)((t + 1) & 1) * (2 * B_ * H_);
        __bf16* hlo_c = hhi_c + B_ * H_;

        // ---- phase A: gate MFMA for step t ----
        f4v acc0 = {0.f, 0.f, 0.f, 0.f};   // hi-product chain
        f4v acc1 = {0.f, 0.f, 0.f, 0.f};   // lo-product chain
        const float* xrow = xs + ((size_t)rowA * T_ + t) * IN_ + kq;
        #pragma unroll
        for (int ks = 0; ks < 16; ++ks) {
            f4v v0 = *(const f4v*)(xrow + ks * 32);
            f4v v1 = *(const f4v*)(xrow + ks * 32 + 4);
            bf8v ah, al;
            #pragma unroll
            for (int j = 0; j < 4; ++j) {
                __bf16 h0 = (__bf16)v0[j], h1 = (__bf16)v1[j];
                ah[j] = h0;  ah[4 + j] = h1;
                al[j]     = (__bf16)(v0[j] - (float)h0);
                al[4 + j] = (__bf16)(v1[j] - (float)h1);
            }
            bf8v w = *(const bf8v*)&Wlds[c][ks * 32 + kq];
            acc0 = __builtin_amdgcn_mfma_f32_16x16x32_bf16(ah, w, acc0, 0, 0, 0);
            acc1 = __builtin_amdgcn_mfma_f32_16x16x32_bf16(al, w, acc1, 0, 0, 0);
        }
        if (t > 0) {
            const __bf16* hh = hhi_p + (size_t)rowA * H_ + kq;
            const __bf16* hl = hlo_p + (size_t)rowA * H_ + kq;
            #pragma unroll
            for (int ks = 0; ks < 32; ++ks) {
                bf8v ah = *(const bf8v*)(hh + ks * 32);
                bf8v al = *(const bf8v*)(hl + ks * 32);
                bf8v w  = *(const bf8v*)&Wlds[c][IN_ + ks * 32 + kq];
                acc0 = __builtin_amdgcn_mfma_f32_16x16x32_bf16(ah, w, acc0, 0, 0, 0);
                acc1 = __builtin_amdgcn_mfma_f32_16x16x32_bf16(al, w, acc1, 0, 0, 0);
            }
        }
        f4v acc = acc0 + acc1;
        #pragma unroll
        for (int r = 0; r < 4; ++r)
            gbuf[wave * 16 + quad * 4 + r][c] = acc[r] + biasv;  // C: col=c, row=quad*4+r

        // ---- phase A2: out-proj partial for step t-1 (reads same h_{t-1}) ----
        if (t > 0) {
            f4v oac = {0.f, 0.f, 0.f, 0.f};
            #pragma unroll
            for (int kk = 0; kk < 8; ++kk) {
                int kbase = wave * 256 + kk * 32 + kq;
                bf8v ah = {}, al = {};
                if (c < 8) {   // A rows 8..15 zero (8 batches per tile)
                    ah = *(const bf8v*)&hhi_p[(size_t)(ob0 + c) * H_ + kbase];
                    al = *(const bf8v*)&hlo_p[(size_t)(ob0 + c) * H_ + kbase];
                }
                oac = __builtin_amdgcn_mfma_f32_16x16x32_bf16(ah, wof[kk], oac, 0, 0, 0);
                oac = __builtin_amdgcn_mfma_f32_16x16x32_bf16(al, wof[kk], oac, 0, 0, 0);
            }
            #pragma unroll
            for (int r = 0; r < 4; ++r)
                obuf[wave][quad * 4 + r][c] = oac[r];
        }
        __syncthreads();

        // ---- phase B: elementwise cell update, write h_t (hi+lo) ----
        {
            float gi = gbuf[bb][jo];
            float gf = gbuf[bb][4 + jo];
            float gg = gbuf[bb][8 + jo];
            float go = gbuf[bb][12 + jo];
            c_reg = sigm(gf) * c_reg + sigm(gi) * tanh_f(gg);
            float hn = sigm(go) * tanh_f(c_reg);
            __bf16 hh = (__bf16)hn;
            hhi_c[(size_t)bb * H_ + j0 + jo] = hh;
            hlo_c[(size_t)bb * H_ + j0 + jo] = (__bf16)(hn - (float)hh);
        }
        // ---- phase B2: reduce out-proj partials, store out[:, t-1, :] ----
        if (t > 0 && tid < 128) {
            int m = tid >> 4, cc = tid & 15;
            float v = obuf[0][m][cc] + obuf[1][m][cc] + obuf[2][m][cc] + obuf[3][m][cc]
                    + bo[oc0 + cc];
            out[(((size_t)(ob0 + m)) * T_ + (t - 1)) * OUT_ + oc0 + cc] = v;
        }

        grid_barrier(cnt8, root, t, blk);   // publish h_t; guards gbuf/obuf WAR
    }

    // ---- epilogue: out-proj for t = T-1 (h_{T-1} is in buffer 0; T even) ----
    {
        const __bf16* hhi_l = hws;
        const __bf16* hlo_l = hws + B_ * H_;
        f4v oac = {0.f, 0.f, 0.f, 0.f};
        #pragma unroll
        for (int kk = 0; kk < 8; ++kk) {
            int kbase = wave * 256 + kk * 32 + kq;
            bf8v ah = {}, al = {};
            if (c < 8) {
                ah = *(const bf8v*)&hhi_l[(size_t)(ob0 + c) * H_ + kbase];
                al = *(const bf8v*)&hlo_l[(size_t)(ob0 + c) * H_ + kbase];
            }
            oac = __builtin_amdgcn_mfma_f32_16x16x32_bf16(ah, wof[kk], oac, 0, 0, 0);
            oac = __builtin_amdgcn_mfma_f32_16x16x32_bf16(al, wof[kk], oac, 0, 0, 0);
        }
        #pragma unroll
        for (int r = 0; r < 4; ++r)
            obuf[wave][quad * 4 + r][c] = oac[r];
        __syncthreads();
        if (tid < 128) {
            int m = tid >> 4, cc = tid & 15;
            float v = obuf[0][m][cc] + obuf[1][m][cc] + obuf[2][m][cc] + obuf[3][m][cc]
                    + bo[oc0 + cc];
            out[(((size_t)(ob0 + m)) * T_ + (T_ - 1)) * OUT_ + oc0 + cc] = v;
        }
    }
}

extern "C" void kernel_launch(void* const* d_in, const int* in_sizes, int n_in,
                              void* d_out, int out_size, void* d_ws, size_t ws_size,
                              hipStream_t stream) {
    const float* xs = (const float*)d_in[0];
    const float* Wi = (const float*)d_in[1];
    const float* Wh = (const float*)d_in[2];
    const float* b  = (const float*)d_in[3];
    const float* Wo = (const float*)d_in[4];
    const float* bo = (const float*)d_in[5];
    float* out = (float*)d_out;

    // ws layout: [0,4K) barrier counters (line-padded, zeroed); [64K,+512K) h
    unsigned* cnt8 = (unsigned*)d_ws;          // 8 counters at cnt8[g*32]
    unsigned* root = cnt8 + 256;               // byte 1024: own 128B line
    __bf16*   hws  = (__bf16*)((char*)d_ws + 65536);

    hipMemsetAsync(d_ws, 0, 4096, stream);     // reset barrier counters (captured)

    void* args[] = {(void*)&xs, (void*)&Wi, (void*)&Wh, (void*)&b,
                    (void*)&Wo, (void*)&bo, (void*)&out, (void*)&hws,
                    (void*)&cnt8, (void*)&root};
    hipLaunchCooperativeKernel((void*)lstm_fused, dim3(256), dim3(256), args, 0, stream);
}